// Round 12
// baseline (573.295 us; speedup 1.0000x reference)
//
#include <hip/hip_runtime.h>
#include <hip/hip_fp16.h>
#include <cstdint>

#define N_NODES 50000
#define IN_DIM  256
#define HID     128
#define OUT_DIM 64
#define N_EDGES 800000
#define BATCH   4096
#define BN_EPS  1e-5f
#define SLOPE   0.01f

typedef unsigned short u16;
typedef __attribute__((ext_vector_type(8))) short bf16x8;
typedef __attribute__((ext_vector_type(4))) float f32x4;

__device__ __forceinline__ u16 f2bf(float f) {
    union { float f; unsigned u; } v; v.f = f;
    unsigned r = v.u + 0x7FFF + ((v.u >> 16) & 1);   // RNE
    return (u16)(r >> 16);
}
__device__ __forceinline__ float bf2f(u16 b) {
    union { unsigned u; float f; } v; v.u = ((unsigned)b) << 16;
    return v.f;
}
__device__ __forceinline__ void splitbf(float v, u16* hi, u16* lo) {
    u16 h = f2bf(v);
    *hi = h;
    *lo = f2bf(v - bf2f(h));
}

// Swizzled B store: element (n,k) of W[128][K] -> fragment-ordered buffer.
__device__ __forceinline__ void swz_store(u16* __restrict__ buf, int K, int n, int k, float v) {
    int KC = K >> 7;
    int chunk = (n >> 6) * KC + (k >> 7);
    int base = chunk * 16384 + ((n >> 4) & 3) * 2048 + ((k >> 5) & 3) * 512
             + (((k >> 3) & 3) * 16 + (n & 15)) * 8 + (k & 7);
    u16 hi, lo;
    splitbf(v, &hi, &lo);
    buf[base] = hi;
    buf[base + 8192] = lo;
}

// BN accumulator: one 64B cache line per scalar (stride 16 floats) to parallelize
// LLC atomic processing across lines.  [theory: R11's 68us = 256k atomics on 4 lines]
#define BNACC_STRIDE 16
#define BNACC_PER_LAYER (256 * BNACC_STRIDE)   // 4096 floats = 16 KB per layer

// ---------------- prep: swizzle-split weights + transpose + zero-init ----------------

#define PW0 (HID * IN_DIM)
#define PW1 (PW0 + HID * HID)
#define PW2 (PW1 + HID * HID)
#define PWD (PW2 + HID * HID)
#define PWT (PWD + HID * HID)
#define POW (PWT + OUT_DIM * HID)
#define PBN (POW + 3 * BNACC_PER_LAYER)
#define PBC (PBN + 256)
#define PEB (PBC + 2 * 3 * 2 * BATCH)
#define PTOT (PEB + 8)

__global__ void prep(const float* __restrict__ w0, const float* __restrict__ w1,
                     const float* __restrict__ w2, const float* __restrict__ WD,
                     const float* __restrict__ WT, const float* __restrict__ out_w,
                     u16* __restrict__ w0swz, u16* __restrict__ w1swz, u16* __restrict__ w2swz,
                     u16* __restrict__ wDTswz,
                     float* __restrict__ wt, float* __restrict__ bnacc3,
                     int* __restrict__ bucketCnt, float* __restrict__ ebuf,
                     int* __restrict__ done) {
    int i = blockIdx.x * 256 + threadIdx.x;
    if (i < PW0) {
        swz_store(w0swz, IN_DIM, i >> 8, i & 255, w0[i]);
    } else if (i < PW1) {
        int j = i - PW0; swz_store(w1swz, HID, j >> 7, j & 127, w1[j]);
    } else if (i < PW2) {
        int j = i - PW1; swz_store(w2swz, HID, j >> 7, j & 127, w2[j]);
    } else if (i < PWD) {
        int j = i - PW2; swz_store(wDTswz, HID, j >> 7, j & 127, WD[j]);
    } else if (i < PWT) {
        int j = i - PWD; swz_store(wDTswz + 32768, HID, j >> 7, j & 127, WT[j]);
    } else if (i < POW) {
        int j = i - PWT;
        wt[j] = out_w[(j & 63) * HID + (j >> 6)];
    } else if (i < PBN) {
        bnacc3[i - POW] = 0.f;
    } else if (i < PBC) {
        bucketCnt[i - PBN] = 0;
    } else if (i < PEB) {
        ebuf[i - PBC] = 0.f;
    } else if (i < PTOT) {
        done[i - PEB] = 0;
    }
}

// ---------------- bucketed CSR build ----------------

#define NBKT 196
#define PASSA_CHUNK 2048
#define NB_A ((N_EDGES + PASSA_CHUNK - 1) / PASSA_CHUNK)

__global__ void bucket_count(const int* __restrict__ dst, int* __restrict__ bucketCnt) {
    __shared__ int hist[NBKT];
    int t = threadIdx.x;
    if (t < NBKT) hist[t] = 0;
    __syncthreads();
    int b0 = blockIdx.x * PASSA_CHUNK;
    int b1 = min(b0 + PASSA_CHUNK, N_EDGES);
    for (int i = b0 + t; i < b1; i += 256)
        atomicAdd(&hist[dst[i] >> 8], 1);
    __syncthreads();
    if (t < NBKT && hist[t] > 0) atomicAdd(&bucketCnt[t], hist[t]);
}

__global__ void bucket_scan(const int* __restrict__ bucketCnt, int* __restrict__ bucketBase,
                            int* __restrict__ gcursor, int* __restrict__ rowstart) {
    __shared__ int s[256];
    int t = threadIdx.x;
    int v = (t < NBKT) ? bucketCnt[t] : 0;
    s[t] = v;
    __syncthreads();
#pragma unroll
    for (int off = 1; off < 256; off <<= 1) {
        int tmp = (t >= off) ? s[t - off] : 0;
        __syncthreads();
        s[t] += tmp;
        __syncthreads();
    }
    if (t < NBKT) { bucketBase[t] = s[t] - v; gcursor[t] = s[t] - v; }
    if (t == 0) { bucketBase[NBKT] = N_EDGES; rowstart[N_NODES] = N_EDGES; }
}

__global__ void bucket_scatter(const int* __restrict__ src, const int* __restrict__ dst,
                               int* __restrict__ gcursor, unsigned* __restrict__ pairs) {
    __shared__ int hist[NBKT], base[NBKT], hist2[NBKT];
    int t = threadIdx.x;
    if (t < NBKT) { hist[t] = 0; hist2[t] = 0; }
    __syncthreads();
    int b0 = blockIdx.x * PASSA_CHUNK;
    int b1 = min(b0 + PASSA_CHUNK, N_EDGES);
    for (int i = b0 + t; i < b1; i += 256)
        atomicAdd(&hist[dst[i] >> 8], 1);
    __syncthreads();
    if (t < NBKT && hist[t] > 0) base[t] = atomicAdd(&gcursor[t], hist[t]);
    __syncthreads();
    for (int i = b0 + t; i < b1; i += 256) {
        int d = dst[i];
        int b = d >> 8;
        int lp = atomicAdd(&hist2[b], 1);
        pairs[base[b] + lp] = ((unsigned)(d & 255) << 16) | (unsigned)src[i];
    }
}

__global__ void bucket_build(const unsigned* __restrict__ pairs, const int* __restrict__ bucketBase,
                             int* __restrict__ rowstart, float* __restrict__ dinv,
                             int* __restrict__ csr) {
    __shared__ int cnt[256], s[256], lcur[256];
    int b = blockIdx.x, t = threadIdx.x;
    int pb0 = bucketBase[b], pb1 = bucketBase[b + 1];
    cnt[t] = 0;
    __syncthreads();
    for (int i = pb0 + t; i < pb1; i += 256)
        atomicAdd(&cnt[pairs[i] >> 16], 1);
    __syncthreads();
    int v = cnt[t];
    s[t] = v;
    __syncthreads();
#pragma unroll
    for (int off = 1; off < 256; off <<= 1) {
        int tmp = (t >= off) ? s[t - off] : 0;
        __syncthreads();
        s[t] += tmp;
        __syncthreads();
    }
    int node = (b << 8) + t;
    int start = pb0 + s[t] - v;
    if (node < N_NODES) {
        rowstart[node] = start;
        dinv[node] = rsqrtf(1.0f + (float)v);
    }
    lcur[t] = start;
    __syncthreads();
    for (int i = pb0 + t; i < pb1; i += 256) {
        unsigned pr = pairs[i];
        int pos = atomicAdd(&lcur[pr >> 16], 1);
        csr[pos] = (int)(pr & 0xFFFFu);
    }
}

__global__ void csr_pack(int* __restrict__ csr, const float* __restrict__ dinv) {
    int e = blockIdx.x * 256 + threadIdx.x;
    if (e < N_EDGES) {
        int sc = csr[e];
        __half hd = __float2half(dinv[sc]);
        csr[e] = ((int)*(u16*)&hd << 16) | sc;
    }
}

// ---------------- swizzled-B LDS MFMA GEMM (layers) ----------------

__global__ __launch_bounds__(256) void gemm_tile(const float* __restrict__ A,
                                                 const float* __restrict__ bnss,
                                                 const u16* __restrict__ Bswz,
                                                 u16* __restrict__ Cout,
                                                 int M, int K) {
    __shared__ u16 Bs[16384];
    const int tid  = threadIdx.x;
    const int wave = tid >> 6, lane = tid & 63;
    const int lr   = lane & 15, quad = lane >> 4;
    const int g    = blockIdx.x & 1;
    const int rowBase = (blockIdx.x >> 1) * 128;
    const int KC = K >> 7;

    f32x4 acc[2][4];
#pragma unroll
    for (int r = 0; r < 2; ++r)
#pragma unroll
        for (int c = 0; c < 4; ++c) acc[r][c] = (f32x4){0.f, 0.f, 0.f, 0.f};

    const int arow0 = rowBase + wave * 32 + lr;
    const int arow1 = arow0 + 16;

    for (int kc = 0; kc < KC; ++kc) {
        if (kc) __syncthreads();
        const uint4* srcB = (const uint4*)(Bswz + (size_t)(g * KC + kc) * 16384);
#pragma unroll
        for (int i = 0; i < 8; ++i)
            ((uint4*)Bs)[i * 256 + tid] = srcB[i * 256 + tid];
        __syncthreads();

#pragma unroll
        for (int kkidx = 0; kkidx < 4; ++kkidx) {
            const int kcol = kc * 128 + kkidx * 32 + quad * 8;
            float av0[8], av1[8];
            if (arow0 < M) {
                const float* ap = A + (size_t)arow0 * K + kcol;
                float4 v0 = ((const float4*)ap)[0];
                float4 v1 = ((const float4*)ap)[1];
                av0[0] = v0.x; av0[1] = v0.y; av0[2] = v0.z; av0[3] = v0.w;
                av0[4] = v1.x; av0[5] = v1.y; av0[6] = v1.z; av0[7] = v1.w;
            } else {
#pragma unroll
                for (int j = 0; j < 8; ++j) av0[j] = 0.f;
            }
            if (arow1 < M) {
                const float* ap = A + (size_t)arow1 * K + kcol;
                float4 v0 = ((const float4*)ap)[0];
                float4 v1 = ((const float4*)ap)[1];
                av1[0] = v0.x; av1[1] = v0.y; av1[2] = v0.z; av1[3] = v0.w;
                av1[4] = v1.x; av1[5] = v1.y; av1[6] = v1.z; av1[7] = v1.w;
            } else {
#pragma unroll
                for (int j = 0; j < 8; ++j) av1[j] = 0.f;
            }
            if (bnss) {
#pragma unroll
                for (int j = 0; j < 8; ++j) {
                    float sc = bnss[kcol + j];
                    float sh = bnss[K + kcol + j];
                    av0[j] = fmaf(av0[j], sc, sh);
                    av1[j] = fmaf(av1[j], sc, sh);
                }
            }
            bf16x8 ah0, al0, ah1, al1;
#pragma unroll
            for (int j = 0; j < 8; ++j) {
                u16 hi, lo;
                splitbf(av0[j], &hi, &lo);
                ((u16*)&ah0)[j] = hi; ((u16*)&al0)[j] = lo;
                splitbf(av1[j], &hi, &lo);
                ((u16*)&ah1)[j] = hi; ((u16*)&al1)[j] = lo;
            }
#pragma unroll
            for (int c = 0; c < 4; ++c) {
                const int lb = c * 2048 + kkidx * 512 + lane * 8;
                bf16x8 bh = *(const bf16x8*)&Bs[lb];
                bf16x8 bl = *(const bf16x8*)&Bs[8192 + lb];
                acc[0][c] = __builtin_amdgcn_mfma_f32_16x16x32_bf16(al0, bh, acc[0][c], 0, 0, 0);
                acc[0][c] = __builtin_amdgcn_mfma_f32_16x16x32_bf16(ah0, bl, acc[0][c], 0, 0, 0);
                acc[0][c] = __builtin_amdgcn_mfma_f32_16x16x32_bf16(ah0, bh, acc[0][c], 0, 0, 0);
                acc[1][c] = __builtin_amdgcn_mfma_f32_16x16x32_bf16(al1, bh, acc[1][c], 0, 0, 0);
                acc[1][c] = __builtin_amdgcn_mfma_f32_16x16x32_bf16(ah1, bl, acc[1][c], 0, 0, 0);
                acc[1][c] = __builtin_amdgcn_mfma_f32_16x16x32_bf16(ah1, bh, acc[1][c], 0, 0, 0);
            }
        }
    }

#pragma unroll
    for (int r = 0; r < 2; ++r) {
        const int rowb = rowBase + wave * 32 + r * 16 + quad * 4;
#pragma unroll
        for (int reg = 0; reg < 4; ++reg) {
            int row = rowb + reg;
            if (row < M) {
#pragma unroll
                for (int c = 0; c < 4; ++c) {
                    int col = g * 64 + c * 16 + lr;
                    __half hv = __float2half(acc[r][c][reg]);
                    Cout[(size_t)row * 128 + col] = *(u16*)&hv;
                }
            }
        }
    }
}

// ---------------- pool GEMM: gathers A from emb on the fly, accumulates e in epilogue ----

__global__ __launch_bounds__(256) void pool_gemm(const float* __restrict__ emb0,
                                                 const float* __restrict__ emb1,
                                                 const float* __restrict__ emb2,
                                                 const float* __restrict__ bnss3,
                                                 const int* __restrict__ dpos, const int* __restrict__ dneg,
                                                 const int* __restrict__ tpos, const int* __restrict__ tneg,
                                                 const u16* __restrict__ wDTswz,
                                                 const float* __restrict__ q_D, const float* __restrict__ q_T,
                                                 float* __restrict__ e_D, float* __restrict__ e_T) {
    __shared__ u16 Bs[16384];
    const int head = blockIdx.y;
    const u16* Bswz = wDTswz + head * 32768;
    const float* q  = head ? q_T : q_D;
    float* eo = head ? e_T : e_D;
    const int* ia = head ? tpos : dpos;
    const int* ib = head ? tneg : dneg;

    const int tid  = threadIdx.x;
    const int wave = tid >> 6, lane = tid & 63;
    const int lr   = lane & 15, quad = lane >> 4;
    const int g    = blockIdx.x & 1;
    const int rowBase = (blockIdx.x >> 1) * 128;

    const int arow0 = rowBase + wave * 32 + lr;
    const int arow1 = arow0 + 16;
    const int l0 = arow0 >> 13, j0 = arow0 & 8191;
    const int l1 = arow1 >> 13, j1 = arow1 & 8191;
    const int node0 = (j0 < BATCH) ? ia[j0] : ib[j0 - BATCH];
    const int node1 = (j1 < BATCH) ? ia[j1] : ib[j1 - BATCH];
    const float* embs[3] = {emb0, emb1, emb2};
    const float* A0 = embs[l0] + (size_t)node0 * HID;
    const float* A1 = embs[l1] + (size_t)node1 * HID;
    const float* bn0 = bnss3 + l0 * 2 * HID;
    const float* bn1 = bnss3 + l1 * 2 * HID;

    f32x4 acc[2][4];
#pragma unroll
    for (int r = 0; r < 2; ++r)
#pragma unroll
        for (int c = 0; c < 4; ++c) acc[r][c] = (f32x4){0.f, 0.f, 0.f, 0.f};

    const uint4* srcB = (const uint4*)(Bswz + (size_t)g * 16384);
#pragma unroll
    for (int i = 0; i < 8; ++i)
        ((uint4*)Bs)[i * 256 + tid] = srcB[i * 256 + tid];
    __syncthreads();

#pragma unroll
    for (int kkidx = 0; kkidx < 4; ++kkidx) {
        const int kcol = kkidx * 32 + quad * 8;
        float av0[8], av1[8];
        {
            float4 v0 = ((const float4*)(A0 + kcol))[0];
            float4 v1 = ((const float4*)(A0 + kcol))[1];
            av0[0] = v0.x; av0[1] = v0.y; av0[2] = v0.z; av0[3] = v0.w;
            av0[4] = v1.x; av0[5] = v1.y; av0[6] = v1.z; av0[7] = v1.w;
            float4 w0 = ((const float4*)(A1 + kcol))[0];
            float4 w1 = ((const float4*)(A1 + kcol))[1];
            av1[0] = w0.x; av1[1] = w0.y; av1[2] = w0.z; av1[3] = w0.w;
            av1[4] = w1.x; av1[5] = w1.y; av1[6] = w1.z; av1[7] = w1.w;
        }
#pragma unroll
        for (int j = 0; j < 8; ++j) {
            av0[j] = fmaf(av0[j], bn0[kcol + j], bn0[HID + kcol + j]);
            av1[j] = fmaf(av1[j], bn1[kcol + j], bn1[HID + kcol + j]);
        }
        bf16x8 ah0, al0, ah1, al1;
#pragma unroll
        for (int j = 0; j < 8; ++j) {
            u16 hi, lo;
            splitbf(av0[j], &hi, &lo);
            ((u16*)&ah0)[j] = hi; ((u16*)&al0)[j] = lo;
            splitbf(av1[j], &hi, &lo);
            ((u16*)&ah1)[j] = hi; ((u16*)&al1)[j] = lo;
        }
#pragma unroll
        for (int c = 0; c < 4; ++c) {
            const int lb = c * 2048 + kkidx * 512 + lane * 8;
            bf16x8 bh = *(const bf16x8*)&Bs[lb];
            bf16x8 bl = *(const bf16x8*)&Bs[8192 + lb];
            acc[0][c] = __builtin_amdgcn_mfma_f32_16x16x32_bf16(al0, bh, acc[0][c], 0, 0, 0);
            acc[0][c] = __builtin_amdgcn_mfma_f32_16x16x32_bf16(ah0, bl, acc[0][c], 0, 0, 0);
            acc[0][c] = __builtin_amdgcn_mfma_f32_16x16x32_bf16(ah0, bh, acc[0][c], 0, 0, 0);
            acc[1][c] = __builtin_amdgcn_mfma_f32_16x16x32_bf16(al1, bh, acc[1][c], 0, 0, 0);
            acc[1][c] = __builtin_amdgcn_mfma_f32_16x16x32_bf16(ah1, bl, acc[1][c], 0, 0, 0);
            acc[1][c] = __builtin_amdgcn_mfma_f32_16x16x32_bf16(ah1, bh, acc[1][c], 0, 0, 0);
        }
    }

    float qv[4];
#pragma unroll
    for (int c = 0; c < 4; ++c) qv[c] = q[g * 64 + c * 16 + lr];
#pragma unroll
    for (int r = 0; r < 2; ++r) {
        const int rowb = rowBase + wave * 32 + r * 16 + quad * 4;
#pragma unroll
        for (int reg = 0; reg < 4; ++reg) {
            float p = 0.f;
#pragma unroll
            for (int c = 0; c < 4; ++c) {
                float v = acc[r][c][reg];
                v = (v > 0.f) ? v : SLOPE * v;
                p = fmaf(v, qv[c], p);
            }
            p += __shfl_xor(p, 1);
            p += __shfl_xor(p, 2);
            p += __shfl_xor(p, 4);
            p += __shfl_xor(p, 8);
            if (lr == 0) atomicAdd(&eo[rowb + reg], p);
        }
    }
}

// ---------------- GCN aggregation (fp16 gather, packed dinv) + bias + relu ----------------

__global__ __launch_bounds__(256) void agg_relu(const u16* __restrict__ h,
                                                const float* __restrict__ dinv,
                                                const int* __restrict__ rowstart,
                                                const int* __restrict__ csr,
                                                const float* __restrict__ bias,
                                                float* __restrict__ out) {
    int wave = threadIdx.x >> 6;
    int lane = threadIdx.x & 63;
    int n = blockIdx.x * 4 + wave;
    if (n >= N_NODES) return;
    int ep = lane >> 5;
    int q  = lane & 31;
    int s = rowstart[n], e1 = rowstart[n + 1];
    float ax = 0.f, ay = 0.f, az = 0.f, aw = 0.f;
    int e = s + ep;
    for (; e + 6 < e1; e += 8) {
        unsigned c0 = (unsigned)csr[e];
        unsigned c1 = (unsigned)csr[e + 2];
        unsigned c2 = (unsigned)csr[e + 4];
        unsigned c3 = (unsigned)csr[e + 6];
        u16 d0 = (u16)(c0 >> 16), d1 = (u16)(c1 >> 16), d2 = (u16)(c2 >> 16), d3 = (u16)(c3 >> 16);
        float dv0 = __half2float(*(const __half*)&d0);
        float dv1 = __half2float(*(const __half*)&d1);
        float dv2 = __half2float(*(const __half*)&d2);
        float dv3 = __half2float(*(const __half*)&d3);
        uint2 w0 = ((const uint2*)(h + (size_t)(c0 & 0xFFFFu) * HID))[q];
        uint2 w1 = ((const uint2*)(h + (size_t)(c1 & 0xFFFFu) * HID))[q];
        uint2 w2 = ((const uint2*)(h + (size_t)(c2 & 0xFFFFu) * HID))[q];
        uint2 w3 = ((const uint2*)(h + (size_t)(c3 & 0xFFFFu) * HID))[q];
        float2 a0 = __half22float2(*(const __half2*)&w0.x), b0 = __half22float2(*(const __half2*)&w0.y);
        float2 a1 = __half22float2(*(const __half2*)&w1.x), b1 = __half22float2(*(const __half2*)&w1.y);
        float2 a2 = __half22float2(*(const __half2*)&w2.x), b2 = __half22float2(*(const __half2*)&w2.y);
        float2 a3 = __half22float2(*(const __half2*)&w3.x), b3 = __half22float2(*(const __half2*)&w3.y);
        ax = fmaf(dv0, a0.x, ax); ay = fmaf(dv0, a0.y, ay); az = fmaf(dv0, b0.x, az); aw = fmaf(dv0, b0.y, aw);
        ax = fmaf(dv1, a1.x, ax); ay = fmaf(dv1, a1.y, ay); az = fmaf(dv1, b1.x, az); aw = fmaf(dv1, b1.y, aw);
        ax = fmaf(dv2, a2.x, ax); ay = fmaf(dv2, a2.y, ay); az = fmaf(dv2, b2.x, az); aw = fmaf(dv2, b2.y, aw);
        ax = fmaf(dv3, a3.x, ax); ay = fmaf(dv3, a3.y, ay); az = fmaf(dv3, b3.x, az); aw = fmaf(dv3, b3.y, aw);
    }
    for (; e < e1; e += 2) {
        unsigned c0 = (unsigned)csr[e];
        u16 d0 = (u16)(c0 >> 16);
        float dv = __half2float(*(const __half*)&d0);
        uint2 w0 = ((const uint2*)(h + (size_t)(c0 & 0xFFFFu) * HID))[q];
        float2 a0 = __half22float2(*(const __half2*)&w0.x);
        float2 b0 = __half22float2(*(const __half2*)&w0.y);
        ax = fmaf(dv, a0.x, ax); ay = fmaf(dv, a0.y, ay);
        az = fmaf(dv, b0.x, az); aw = fmaf(dv, b0.y, aw);
    }
    ax += __shfl_xor(ax, 32);
    ay += __shfl_xor(ay, 32);
    az += __shfl_xor(az, 32);
    aw += __shfl_xor(aw, 32);
    if (ep == 0) {
        float dn = dinv[n];
        float dn2 = dn * dn;
        uint2 hw = ((const uint2*)(h + (size_t)n * HID))[q];
        float2 h0 = __half22float2(*(const __half2*)&hw.x);
        float2 h1 = __half22float2(*(const __half2*)&hw.y);
        float4 bv = ((const float4*)bias)[q];
        float4 o;
        o.x = fmaxf(fmaf(ax, dn, fmaf(h0.x, dn2, bv.x)), 0.f);
        o.y = fmaxf(fmaf(ay, dn, fmaf(h0.y, dn2, bv.y)), 0.f);
        o.z = fmaxf(fmaf(az, dn, fmaf(h1.x, dn2, bv.z)), 0.f);
        o.w = fmaxf(fmaf(aw, dn, fmaf(h1.y, dn2, bv.w)), 0.f);
        ((float4*)(out + (size_t)n * HID))[q] = o;
    }
}

// ---------------- BatchNorm reduce + fused finalize (line-padded accumulator) ----------

#define BNR_NB 1000

__global__ __launch_bounds__(256) void bn_reduce_fin(const float* __restrict__ x,
                                                     float* __restrict__ acc,   // stride-16 padded
                                                     int* __restrict__ done,
                                                     const float* __restrict__ gamma,
                                                     const float* __restrict__ beta,
                                                     float* __restrict__ bnss) {
    __shared__ float s_s[HID], s_sq[HID];
    int tid = threadIdx.x;
    if (tid < HID) { s_s[tid] = 0.f; s_sq[tid] = 0.f; }
    __syncthreads();
    int q  = tid & 31;     // float4 column index
    int rp = tid >> 5;     // 8 row streams
    const int RPB = (N_NODES + BNR_NB - 1) / BNR_NB;   // 50
    int r0 = blockIdx.x * RPB;
    int r1 = min(r0 + RPB, N_NODES);
    float sx = 0.f, sy = 0.f, sz = 0.f, sw = 0.f;
    float qx = 0.f, qy = 0.f, qz = 0.f, qw = 0.f;
    for (int r = r0 + rp; r < r1; r += 8) {
        float4 v = ((const float4*)(x + (size_t)r * HID))[q];
        sx += v.x; sy += v.y; sz += v.z; sw += v.w;
        qx = fmaf(v.x, v.x, qx); qy = fmaf(v.y, v.y, qy);
        qz = fmaf(v.z, v.z, qz); qw = fmaf(v.w, v.w, qw);
    }
    atomicAdd(&s_s[q * 4 + 0], sx);
    atomicAdd(&s_s[q * 4 + 1], sy);
    atomicAdd(&s_s[q * 4 + 2], sz);
    atomicAdd(&s_s[q * 4 + 3], sw);
    atomicAdd(&s_sq[q * 4 + 0], qx);
    atomicAdd(&s_sq[q * 4 + 1], qy);
    atomicAdd(&s_sq[q * 4 + 2], qz);
    atomicAdd(&s_sq[q * 4 + 3], qw);
    __syncthreads();
    // one 64B line per accumulator -> LLC processes the 256 streams in parallel
    if (tid < HID) atomicAdd(&acc[tid * BNACC_STRIDE], s_s[tid]);
    else           atomicAdd(&acc[tid * BNACC_STRIDE], s_sq[tid - HID]);
    __threadfence();
    __shared__ int isLast;
    if (tid == 0)
        isLast = (atomicAdd(done, 1) == gridDim.x - 1);
    __syncthreads();
    if (isLast && tid < HID) {
        float st  = atomicAdd(&acc[tid * BNACC_STRIDE], 0.f);            // coherent read
        float sqt = atomicAdd(&acc[(HID + tid) * BNACC_STRIDE], 0.f);
        float mean = st * (1.0f / N_NODES);
        float var  = fmaxf(sqt * (1.0f / N_NODES) - mean * mean, 0.f);
        float sc   = gamma[tid] * rsqrtf(var + BN_EPS);
        bnss[tid] = sc;
        bnss[HID + tid] = beta[tid] - mean * sc;
    }
}

// ---------------- softmax + pool (gathers emb directly, BN fused) ----------------

__global__ void softmax_pool(const float* __restrict__ e0, const float* __restrict__ e1,
                             const float* __restrict__ e2, const float* __restrict__ bnss3,
                             const int* __restrict__ dpos, const int* __restrict__ dneg,
                             const int* __restrict__ tpos, const int* __restrict__ tneg,
                             const float* __restrict__ e_D, const float* __restrict__ e_T,
                             float* __restrict__ P_D, float* __restrict__ P_T) {
    int j = blockIdx.x;
    int f = threadIdx.x;
    int head = blockIdx.y;
    const int* ia = head ? tpos : dpos;
    const int* ib = head ? tneg : dneg;
    const float* e = head ? e_T : e_D;
    float* P = head ? P_T : P_D;
    int node = (j < BATCH) ? ia[j] : ib[j - BATCH];
    float l0 = e[j], l1 = e[2 * BATCH + j], l2 = e[4 * BATCH + j];
    float m = fmaxf(l0, fmaxf(l1, l2));
    float a0 = expf(l0 - m), a1 = expf(l1 - m), a2 = expf(l2 - m);
    float inv = 1.0f / (a0 + a1 + a2);
    float v0 = fmaf(e0[(size_t)node * HID + f], bnss3[f],           bnss3[HID + f]);
    float v1 = fmaf(e1[(size_t)node * HID + f], bnss3[2 * HID + f], bnss3[3 * HID + f]);
    float v2 = fmaf(e2[(size_t)node * HID + f], bnss3[4 * HID + f], bnss3[5 * HID + f]);
    P[(size_t)j * HID + f] = (a0 * v0 + a1 * v1 + a2 * v2) * inv;
}

// ---------------- output head: 4 segments batched via blockIdx.y ----------------

__global__ __launch_bounds__(256) void head_gemm(const float* __restrict__ P_D,
                                                 const float* __restrict__ P_T,
                                                 const float* __restrict__ B,
                                                 const float* __restrict__ bias,
                                                 float* __restrict__ out) {
    constexpr int BM = 64, BK = 32, BN = OUT_DIM, TM = 4, TN = 4;
    __shared__ float As[BK][BM];
    __shared__ float Bs[BK][BN];
    const int y = blockIdx.y;
    const float* A = ((y & 1) ? P_T : P_D) + (size_t)(y >> 1) * BATCH * HID;
    float* C = out + (size_t)y * BATCH * OUT_DIM;
    const int tid = threadIdx.x;
    const int tx = tid & 15, ty = tid >> 4;
    const int rowBase = blockIdx.x * BM;
    float acc[TM][TN];
#pragma unroll
    for (int i = 0; i < TM; ++i)
#pragma unroll
        for (int j = 0; j < TN; ++j) acc[i][j] = 0.f;

    for (int kk = 0; kk < HID; kk += BK) {
#pragma unroll
        for (int i = tid; i < (BM * BK) / 4; i += 256) {
            int m  = i >> 3;
            int kq = i & 7;
            float4 v = *(const float4*)(A + (size_t)(rowBase + m) * HID + kk + kq * 4);
            As[kq * 4 + 0][m] = v.x;
            As[kq * 4 + 1][m] = v.y;
            As[kq * 4 + 2][m] = v.z;
            As[kq * 4 + 3][m] = v.w;
        }
#pragma unroll
        for (int i = tid; i < (BK * BN) / 4; i += 256) {
            int k  = i / (BN / 4);
            int n4 = i % (BN / 4);
            *(float4*)&Bs[k][n4 * 4] = *(const float4*)(B + (size_t)(kk + k) * BN + n4 * 4);
        }
        __syncthreads();
#pragma unroll 8
        for (int k = 0; k < BK; ++k) {
            float a[TM], b[TN];
#pragma unroll
            for (int i = 0; i < TM; ++i) a[i] = As[k][ty * TM + i];
#pragma unroll
            for (int j = 0; j < TN; ++j) b[j] = Bs[k][tx * TN + j];
#pragma unroll
            for (int i = 0; i < TM; ++i)
#pragma unroll
                for (int j = 0; j < TN; ++j)
                    acc[i][j] = fmaf(a[i], b[j], acc[i][j]);
        }
        __syncthreads();
    }
#pragma unroll
    for (int i = 0; i < TM; ++i) {
        int grow = rowBase + ty * TM + i;
#pragma unroll
        for (int j = 0; j < TN; ++j)
            C[(size_t)grow * BN + tx * TN + j] = acc[i][j] + bias[tx * TN + j];
    }
}

// ---------------- host ----------------

extern "C" void kernel_launch(void* const* d_in, const int* in_sizes, int n_in,
                              void* d_out, int out_size, void* d_ws, size_t ws_size,
                              hipStream_t stream) {
    const float* x          = (const float*)d_in[0];
    const int*   ei         = (const int*)d_in[1];
    const int*   srcp       = ei;
    const int*   dstp       = ei + N_EDGES;
    const int*   drug_pos   = (const int*)d_in[2];
    const int*   target_pos = (const int*)d_in[3];
    const int*   drug_neg   = (const int*)d_in[4];
    const int*   target_neg = (const int*)d_in[5];
    const float* gcn_w[3]   = {(const float*)d_in[7], (const float*)d_in[9], (const float*)d_in[11]};
    const float* gcn_b[3]   = {(const float*)d_in[8], (const float*)d_in[10], (const float*)d_in[12]};
    const float* gamma      = (const float*)d_in[13];
    const float* beta       = (const float*)d_in[14];
    const float* W_D        = (const float*)d_in[15];
    const float* W_T        = (const float*)d_in[16];
    const float* q_D        = (const float*)d_in[17];
    const float* q_T        = (const float*)d_in[18];
    const float* out_w      = (const float*)d_in[19];
    const float* out_b      = (const float*)d_in[20];
    float*       out        = (float*)d_out;

    // ---- workspace (~110 MB) with phase overlays ----
    char* p = (char*)d_ws;
    auto alloc = [&](size_t bytes) -> char* {
        char* r = p;
        p += (bytes + 255) & ~(size_t)255;
        return r;
    };
    char*  reg1  = alloc(sizeof(float) * (size_t)N_NODES * HID);   // h (fp16) | P_D+P_T
    float* emb0  = (float*)alloc(sizeof(float) * (size_t)N_NODES * HID);
    float* emb1  = (float*)alloc(sizeof(float) * (size_t)N_NODES * HID);
    float* emb2  = (float*)alloc(sizeof(float) * (size_t)N_NODES * HID);
    float* ebuf  = (float*)alloc(sizeof(float) * (size_t)2 * 3 * 2 * BATCH);
    u16*   w0swz = (u16*)alloc(sizeof(u16) * 2 * HID * IN_DIM);
    u16*   w1swz = (u16*)alloc(sizeof(u16) * 2 * HID * HID);
    u16*   w2swz = (u16*)alloc(sizeof(u16) * 2 * HID * HID);
    u16*   wDTswz = (u16*)alloc(sizeof(u16) * 4 * HID * HID);
    float* wt    = (float*)alloc(sizeof(float) * OUT_DIM * HID);
    int*   rowstart = (int*)alloc(sizeof(int) * (N_NODES + 1));
    int*   csr   = (int*)alloc(sizeof(int) * N_EDGES);
    unsigned* pairs = (unsigned*)alloc(sizeof(unsigned) * N_EDGES);
    float* dinvp = (float*)alloc(sizeof(float) * N_NODES);
    int*   bucketCnt  = (int*)alloc(sizeof(int) * 256);
    int*   bucketBase = (int*)alloc(sizeof(int) * (NBKT + 1));
    int*   gcursor    = (int*)alloc(sizeof(int) * 256);
    float* bnacc3 = (float*)alloc(sizeof(float) * 3 * BNACC_PER_LAYER);
    float* bnss3  = (float*)alloc(sizeof(float) * 3 * 2 * HID);
    int*   done   = (int*)alloc(sizeof(int) * 8);
    if ((size_t)(p - (char*)d_ws) > ws_size) return;   // visible failure if ws too small

    u16*   hbuf = (u16*)reg1;
    float* P_D  = (float*)reg1;                         // pools phase: h is dead
    float* P_T  = P_D + (size_t)2 * BATCH * HID;
    float* e_D  = ebuf;
    float* e_T  = ebuf + 3 * 2 * BATCH;
    float* embp[3] = {emb0, emb1, emb2};
    const u16* wswz[3] = {w0swz, w1swz, w2swz};

    // ---- prep ----
    prep<<<(PTOT + 255) / 256, 256, 0, stream>>>(
        gcn_w[0], gcn_w[1], gcn_w[2], W_D, W_T, out_w,
        w0swz, w1swz, w2swz, wDTswz, wt, bnacc3, bucketCnt, ebuf, done);

    // ---- bucketed CSR build ----
    bucket_count<<<NB_A, 256, 0, stream>>>(dstp, bucketCnt);
    bucket_scan<<<1, 256, 0, stream>>>(bucketCnt, bucketBase, gcursor, rowstart);
    bucket_scatter<<<NB_A, 256, 0, stream>>>(srcp, dstp, gcursor, pairs);
    bucket_build<<<NBKT, 256, 0, stream>>>(pairs, bucketBase, rowstart, dinvp, csr);
    csr_pack<<<(N_EDGES + 255) / 256, 256, 0, stream>>>(csr, dinvp);

    // ---- 3 GCN layers (BN fused into next consumer) ----
    const int GB = ((N_NODES + 127) / 128) * 2;   // 782 blocks
    for (int l = 0; l < 3; ++l) {
        int din = (l == 0) ? IN_DIM : HID;
        const float* Ain = (l == 0) ? x : embp[l - 1];
        const float* bnss = (l == 0) ? nullptr : (bnss3 + (l - 1) * 2 * HID);
        gemm_tile<<<GB, 256, 0, stream>>>(Ain, bnss, wswz[l], hbuf, N_NODES, din);
        agg_relu<<<(N_NODES + 3) / 4, 256, 0, stream>>>(hbuf, dinvp, rowstart, csr, gcn_b[l], embp[l]);
        bn_reduce_fin<<<BNR_NB, 256, 0, stream>>>(embp[l], bnacc3 + l * BNACC_PER_LAYER, done + l,
                                                  gamma, beta, bnss3 + l * 2 * HID);
    }

    // ---- attention pooling (H never materialized; e accumulated in pool_gemm) ----
    const int RG = 3 * 2 * BATCH;
    pool_gemm<<<dim3((RG / 128) * 2, 2), 256, 0, stream>>>(
        emb0, emb1, emb2, bnss3, drug_pos, drug_neg, target_pos, target_neg,
        wDTswz, q_D, q_T, e_D, e_T);
    softmax_pool<<<dim3(2 * BATCH, 2), HID, 0, stream>>>(
        emb0, emb1, emb2, bnss3, drug_pos, drug_neg, target_pos, target_neg,
        e_D, e_T, P_D, P_T);

    // ---- output head ----
    head_gemm<<<dim3(BATCH / 64, 4), 256, 0, stream>>>(P_D, P_T, wt, out_b, out);
}

// Round 13
// 465.451 us; speedup vs baseline: 1.2317x; 1.2317x over previous
//
#include <hip/hip_runtime.h>
#include <hip/hip_fp16.h>
#include <cstdint>

#define N_NODES 50000
#define IN_DIM  256
#define HID     128
#define OUT_DIM 64
#define N_EDGES 800000
#define BATCH   4096
#define BN_EPS  1e-5f
#define SLOPE   0.01f

typedef unsigned short u16;
typedef __attribute__((ext_vector_type(8))) short bf16x8;
typedef __attribute__((ext_vector_type(4))) float f32x4;

__device__ __forceinline__ u16 f2bf(float f) {
    union { float f; unsigned u; } v; v.f = f;
    unsigned r = v.u + 0x7FFF + ((v.u >> 16) & 1);   // RNE
    return (u16)(r >> 16);
}
__device__ __forceinline__ float bf2f(u16 b) {
    union { unsigned u; float f; } v; v.u = ((unsigned)b) << 16;
    return v.f;
}
__device__ __forceinline__ void splitbf(float v, u16* hi, u16* lo) {
    u16 h = f2bf(v);
    *hi = h;
    *lo = f2bf(v - bf2f(h));
}

// Swizzled B store: element (n,k) of W[128][K] -> fragment-ordered buffer.
__device__ __forceinline__ void swz_store(u16* __restrict__ buf, int K, int n, int k, float v) {
    int KC = K >> 7;
    int chunk = (n >> 6) * KC + (k >> 7);
    int base = chunk * 16384 + ((n >> 4) & 3) * 2048 + ((k >> 5) & 3) * 512
             + (((k >> 3) & 3) * 16 + (n & 15)) * 8 + (k & 7);
    u16 hi, lo;
    splitbf(v, &hi, &lo);
    buf[base] = hi;
    buf[base + 8192] = lo;
}

// BN accumulator: stride-16 padded (one 64B line per scalar; harmless, kept from R12)
#define BNACC_STRIDE 16
#define BNACC_PER_LAYER (256 * BNACC_STRIDE)   // 4096 floats = 16 KB per layer

// ---------------- prep: swizzle-split weights + transpose + zero-init ----------------

#define PW0 (HID * IN_DIM)
#define PW1 (PW0 + HID * HID)
#define PW2 (PW1 + HID * HID)
#define PWD (PW2 + HID * HID)
#define PWT (PWD + HID * HID)
#define POW (PWT + OUT_DIM * HID)
#define PBN (POW + 3 * BNACC_PER_LAYER)
#define PBC (PBN + 256)
#define PTOT (PBC + 2 * 3 * 2 * BATCH)

__global__ void prep(const float* __restrict__ w0, const float* __restrict__ w1,
                     const float* __restrict__ w2, const float* __restrict__ WD,
                     const float* __restrict__ WT, const float* __restrict__ out_w,
                     u16* __restrict__ w0swz, u16* __restrict__ w1swz, u16* __restrict__ w2swz,
                     u16* __restrict__ wDTswz,
                     float* __restrict__ wt, float* __restrict__ bnacc3,
                     int* __restrict__ bucketCnt, float* __restrict__ ebuf) {
    int i = blockIdx.x * 256 + threadIdx.x;
    if (i < PW0) {
        swz_store(w0swz, IN_DIM, i >> 8, i & 255, w0[i]);
    } else if (i < PW1) {
        int j = i - PW0; swz_store(w1swz, HID, j >> 7, j & 127, w1[j]);
    } else if (i < PW2) {
        int j = i - PW1; swz_store(w2swz, HID, j >> 7, j & 127, w2[j]);
    } else if (i < PWD) {
        int j = i - PW2; swz_store(wDTswz, HID, j >> 7, j & 127, WD[j]);
    } else if (i < PWT) {
        int j = i - PWD; swz_store(wDTswz + 32768, HID, j >> 7, j & 127, WT[j]);
    } else if (i < POW) {
        int j = i - PWT;
        wt[j] = out_w[(j & 63) * HID + (j >> 6)];
    } else if (i < PBN) {
        bnacc3[i - POW] = 0.f;
    } else if (i < PBC) {
        bucketCnt[i - PBN] = 0;
    } else if (i < PTOT) {
        ebuf[i - PBC] = 0.f;
    }
}

// ---------------- bucketed CSR build ----------------

#define NBKT 196
#define PASSA_CHUNK 2048
#define NB_A ((N_EDGES + PASSA_CHUNK - 1) / PASSA_CHUNK)

__global__ void bucket_count(const int* __restrict__ dst, int* __restrict__ bucketCnt) {
    __shared__ int hist[NBKT];
    int t = threadIdx.x;
    if (t < NBKT) hist[t] = 0;
    __syncthreads();
    int b0 = blockIdx.x * PASSA_CHUNK;
    int b1 = min(b0 + PASSA_CHUNK, N_EDGES);
    for (int i = b0 + t; i < b1; i += 256)
        atomicAdd(&hist[dst[i] >> 8], 1);
    __syncthreads();
    if (t < NBKT && hist[t] > 0) atomicAdd(&bucketCnt[t], hist[t]);
}

__global__ void bucket_scan(const int* __restrict__ bucketCnt, int* __restrict__ bucketBase,
                            int* __restrict__ gcursor, int* __restrict__ rowstart) {
    __shared__ int s[256];
    int t = threadIdx.x;
    int v = (t < NBKT) ? bucketCnt[t] : 0;
    s[t] = v;
    __syncthreads();
#pragma unroll
    for (int off = 1; off < 256; off <<= 1) {
        int tmp = (t >= off) ? s[t - off] : 0;
        __syncthreads();
        s[t] += tmp;
        __syncthreads();
    }
    if (t < NBKT) { bucketBase[t] = s[t] - v; gcursor[t] = s[t] - v; }
    if (t == 0) { bucketBase[NBKT] = N_EDGES; rowstart[N_NODES] = N_EDGES; }
}

__global__ void bucket_scatter(const int* __restrict__ src, const int* __restrict__ dst,
                               int* __restrict__ gcursor, unsigned* __restrict__ pairs) {
    __shared__ int hist[NBKT], base[NBKT], hist2[NBKT];
    int t = threadIdx.x;
    if (t < NBKT) { hist[t] = 0; hist2[t] = 0; }
    __syncthreads();
    int b0 = blockIdx.x * PASSA_CHUNK;
    int b1 = min(b0 + PASSA_CHUNK, N_EDGES);
    for (int i = b0 + t; i < b1; i += 256)
        atomicAdd(&hist[dst[i] >> 8], 1);
    __syncthreads();
    if (t < NBKT && hist[t] > 0) base[t] = atomicAdd(&gcursor[t], hist[t]);
    __syncthreads();
    for (int i = b0 + t; i < b1; i += 256) {
        int d = dst[i];
        int b = d >> 8;
        int lp = atomicAdd(&hist2[b], 1);
        pairs[base[b] + lp] = ((unsigned)(d & 255) << 16) | (unsigned)src[i];
    }
}

__global__ void bucket_build(const unsigned* __restrict__ pairs, const int* __restrict__ bucketBase,
                             int* __restrict__ rowstart, float* __restrict__ dinv,
                             int* __restrict__ csr) {
    __shared__ int cnt[256], s[256], lcur[256];
    int b = blockIdx.x, t = threadIdx.x;
    int pb0 = bucketBase[b], pb1 = bucketBase[b + 1];
    cnt[t] = 0;
    __syncthreads();
    for (int i = pb0 + t; i < pb1; i += 256)
        atomicAdd(&cnt[pairs[i] >> 16], 1);
    __syncthreads();
    int v = cnt[t];
    s[t] = v;
    __syncthreads();
#pragma unroll
    for (int off = 1; off < 256; off <<= 1) {
        int tmp = (t >= off) ? s[t - off] : 0;
        __syncthreads();
        s[t] += tmp;
        __syncthreads();
    }
    int node = (b << 8) + t;
    int start = pb0 + s[t] - v;
    if (node < N_NODES) {
        rowstart[node] = start;
        dinv[node] = rsqrtf(1.0f + (float)v);
    }
    lcur[t] = start;
    __syncthreads();
    for (int i = pb0 + t; i < pb1; i += 256) {
        unsigned pr = pairs[i];
        int pos = atomicAdd(&lcur[pr >> 16], 1);
        csr[pos] = (int)(pr & 0xFFFFu);
    }
}

__global__ void csr_pack(int* __restrict__ csr, const float* __restrict__ dinv) {
    int e = blockIdx.x * 256 + threadIdx.x;
    if (e < N_EDGES) {
        int sc = csr[e];
        __half hd = __float2half(dinv[sc]);
        csr[e] = ((int)*(u16*)&hd << 16) | sc;
    }
}

// ---------------- swizzled-B LDS MFMA GEMM (layers) ----------------

__global__ __launch_bounds__(256) void gemm_tile(const float* __restrict__ A,
                                                 const float* __restrict__ bnss,
                                                 const u16* __restrict__ Bswz,
                                                 u16* __restrict__ Cout,
                                                 int M, int K) {
    __shared__ u16 Bs[16384];
    const int tid  = threadIdx.x;
    const int wave = tid >> 6, lane = tid & 63;
    const int lr   = lane & 15, quad = lane >> 4;
    const int g    = blockIdx.x & 1;
    const int rowBase = (blockIdx.x >> 1) * 128;
    const int KC = K >> 7;

    f32x4 acc[2][4];
#pragma unroll
    for (int r = 0; r < 2; ++r)
#pragma unroll
        for (int c = 0; c < 4; ++c) acc[r][c] = (f32x4){0.f, 0.f, 0.f, 0.f};

    const int arow0 = rowBase + wave * 32 + lr;
    const int arow1 = arow0 + 16;

    for (int kc = 0; kc < KC; ++kc) {
        if (kc) __syncthreads();
        const uint4* srcB = (const uint4*)(Bswz + (size_t)(g * KC + kc) * 16384);
#pragma unroll
        for (int i = 0; i < 8; ++i)
            ((uint4*)Bs)[i * 256 + tid] = srcB[i * 256 + tid];
        __syncthreads();

#pragma unroll
        for (int kkidx = 0; kkidx < 4; ++kkidx) {
            const int kcol = kc * 128 + kkidx * 32 + quad * 8;
            float av0[8], av1[8];
            if (arow0 < M) {
                const float* ap = A + (size_t)arow0 * K + kcol;
                float4 v0 = ((const float4*)ap)[0];
                float4 v1 = ((const float4*)ap)[1];
                av0[0] = v0.x; av0[1] = v0.y; av0[2] = v0.z; av0[3] = v0.w;
                av0[4] = v1.x; av0[5] = v1.y; av0[6] = v1.z; av0[7] = v1.w;
            } else {
#pragma unroll
                for (int j = 0; j < 8; ++j) av0[j] = 0.f;
            }
            if (arow1 < M) {
                const float* ap = A + (size_t)arow1 * K + kcol;
                float4 v0 = ((const float4*)ap)[0];
                float4 v1 = ((const float4*)ap)[1];
                av1[0] = v0.x; av1[1] = v0.y; av1[2] = v0.z; av1[3] = v0.w;
                av1[4] = v1.x; av1[5] = v1.y; av1[6] = v1.z; av1[7] = v1.w;
            } else {
#pragma unroll
                for (int j = 0; j < 8; ++j) av1[j] = 0.f;
            }
            if (bnss) {
#pragma unroll
                for (int j = 0; j < 8; ++j) {
                    float sc = bnss[kcol + j];
                    float sh = bnss[K + kcol + j];
                    av0[j] = fmaf(av0[j], sc, sh);
                    av1[j] = fmaf(av1[j], sc, sh);
                }
            }
            bf16x8 ah0, al0, ah1, al1;
#pragma unroll
            for (int j = 0; j < 8; ++j) {
                u16 hi, lo;
                splitbf(av0[j], &hi, &lo);
                ((u16*)&ah0)[j] = hi; ((u16*)&al0)[j] = lo;
                splitbf(av1[j], &hi, &lo);
                ((u16*)&ah1)[j] = hi; ((u16*)&al1)[j] = lo;
            }
#pragma unroll
            for (int c = 0; c < 4; ++c) {
                const int lb = c * 2048 + kkidx * 512 + lane * 8;
                bf16x8 bh = *(const bf16x8*)&Bs[lb];
                bf16x8 bl = *(const bf16x8*)&Bs[8192 + lb];
                acc[0][c] = __builtin_amdgcn_mfma_f32_16x16x32_bf16(al0, bh, acc[0][c], 0, 0, 0);
                acc[0][c] = __builtin_amdgcn_mfma_f32_16x16x32_bf16(ah0, bl, acc[0][c], 0, 0, 0);
                acc[0][c] = __builtin_amdgcn_mfma_f32_16x16x32_bf16(ah0, bh, acc[0][c], 0, 0, 0);
                acc[1][c] = __builtin_amdgcn_mfma_f32_16x16x32_bf16(al1, bh, acc[1][c], 0, 0, 0);
                acc[1][c] = __builtin_amdgcn_mfma_f32_16x16x32_bf16(ah1, bl, acc[1][c], 0, 0, 0);
                acc[1][c] = __builtin_amdgcn_mfma_f32_16x16x32_bf16(ah1, bh, acc[1][c], 0, 0, 0);
            }
        }
    }

#pragma unroll
    for (int r = 0; r < 2; ++r) {
        const int rowb = rowBase + wave * 32 + r * 16 + quad * 4;
#pragma unroll
        for (int reg = 0; reg < 4; ++reg) {
            int row = rowb + reg;
            if (row < M) {
#pragma unroll
                for (int c = 0; c < 4; ++c) {
                    int col = g * 64 + c * 16 + lr;
                    __half hv = __float2half(acc[r][c][reg]);
                    Cout[(size_t)row * 128 + col] = *(u16*)&hv;
                }
            }
        }
    }
}

// ---------------- pool GEMM: gathers A from emb on the fly, accumulates e in epilogue ----

__global__ __launch_bounds__(256) void pool_gemm(const float* __restrict__ emb0,
                                                 const float* __restrict__ emb1,
                                                 const float* __restrict__ emb2,
                                                 const float* __restrict__ bnss3,
                                                 const int* __restrict__ dpos, const int* __restrict__ dneg,
                                                 const int* __restrict__ tpos, const int* __restrict__ tneg,
                                                 const u16* __restrict__ wDTswz,
                                                 const float* __restrict__ q_D, const float* __restrict__ q_T,
                                                 float* __restrict__ e_D, float* __restrict__ e_T) {
    __shared__ u16 Bs[16384];
    const int head = blockIdx.y;
    const u16* Bswz = wDTswz + head * 32768;
    const float* q  = head ? q_T : q_D;
    float* eo = head ? e_T : e_D;
    const int* ia = head ? tpos : dpos;
    const int* ib = head ? tneg : dneg;

    const int tid  = threadIdx.x;
    const int wave = tid >> 6, lane = tid & 63;
    const int lr   = lane & 15, quad = lane >> 4;
    const int g    = blockIdx.x & 1;
    const int rowBase = (blockIdx.x >> 1) * 128;

    const int arow0 = rowBase + wave * 32 + lr;
    const int arow1 = arow0 + 16;
    const int l0 = arow0 >> 13, j0 = arow0 & 8191;
    const int l1 = arow1 >> 13, j1 = arow1 & 8191;
    const int node0 = (j0 < BATCH) ? ia[j0] : ib[j0 - BATCH];
    const int node1 = (j1 < BATCH) ? ia[j1] : ib[j1 - BATCH];
    const float* embs[3] = {emb0, emb1, emb2};
    const float* A0 = embs[l0] + (size_t)node0 * HID;
    const float* A1 = embs[l1] + (size_t)node1 * HID;
    const float* bn0 = bnss3 + l0 * 2 * HID;
    const float* bn1 = bnss3 + l1 * 2 * HID;

    f32x4 acc[2][4];
#pragma unroll
    for (int r = 0; r < 2; ++r)
#pragma unroll
        for (int c = 0; c < 4; ++c) acc[r][c] = (f32x4){0.f, 0.f, 0.f, 0.f};

    const uint4* srcB = (const uint4*)(Bswz + (size_t)g * 16384);
#pragma unroll
    for (int i = 0; i < 8; ++i)
        ((uint4*)Bs)[i * 256 + tid] = srcB[i * 256 + tid];
    __syncthreads();

#pragma unroll
    for (int kkidx = 0; kkidx < 4; ++kkidx) {
        const int kcol = kkidx * 32 + quad * 8;
        float av0[8], av1[8];
        {
            float4 v0 = ((const float4*)(A0 + kcol))[0];
            float4 v1 = ((const float4*)(A0 + kcol))[1];
            av0[0] = v0.x; av0[1] = v0.y; av0[2] = v0.z; av0[3] = v0.w;
            av0[4] = v1.x; av0[5] = v1.y; av0[6] = v1.z; av0[7] = v1.w;
            float4 w0 = ((const float4*)(A1 + kcol))[0];
            float4 w1 = ((const float4*)(A1 + kcol))[1];
            av1[0] = w0.x; av1[1] = w0.y; av1[2] = w0.z; av1[3] = w0.w;
            av1[4] = w1.x; av1[5] = w1.y; av1[6] = w1.z; av1[7] = w1.w;
        }
#pragma unroll
        for (int j = 0; j < 8; ++j) {
            av0[j] = fmaf(av0[j], bn0[kcol + j], bn0[HID + kcol + j]);
            av1[j] = fmaf(av1[j], bn1[kcol + j], bn1[HID + kcol + j]);
        }
        bf16x8 ah0, al0, ah1, al1;
#pragma unroll
        for (int j = 0; j < 8; ++j) {
            u16 hi, lo;
            splitbf(av0[j], &hi, &lo);
            ((u16*)&ah0)[j] = hi; ((u16*)&al0)[j] = lo;
            splitbf(av1[j], &hi, &lo);
            ((u16*)&ah1)[j] = hi; ((u16*)&al1)[j] = lo;
        }
#pragma unroll
        for (int c = 0; c < 4; ++c) {
            const int lb = c * 2048 + kkidx * 512 + lane * 8;
            bf16x8 bh = *(const bf16x8*)&Bs[lb];
            bf16x8 bl = *(const bf16x8*)&Bs[8192 + lb];
            acc[0][c] = __builtin_amdgcn_mfma_f32_16x16x32_bf16(al0, bh, acc[0][c], 0, 0, 0);
            acc[0][c] = __builtin_amdgcn_mfma_f32_16x16x32_bf16(ah0, bl, acc[0][c], 0, 0, 0);
            acc[0][c] = __builtin_amdgcn_mfma_f32_16x16x32_bf16(ah0, bh, acc[0][c], 0, 0, 0);
            acc[1][c] = __builtin_amdgcn_mfma_f32_16x16x32_bf16(al1, bh, acc[1][c], 0, 0, 0);
            acc[1][c] = __builtin_amdgcn_mfma_f32_16x16x32_bf16(ah1, bl, acc[1][c], 0, 0, 0);
            acc[1][c] = __builtin_amdgcn_mfma_f32_16x16x32_bf16(ah1, bh, acc[1][c], 0, 0, 0);
        }
    }

    float qv[4];
#pragma unroll
    for (int c = 0; c < 4; ++c) qv[c] = q[g * 64 + c * 16 + lr];
#pragma unroll
    for (int r = 0; r < 2; ++r) {
        const int rowb = rowBase + wave * 32 + r * 16 + quad * 4;
#pragma unroll
        for (int reg = 0; reg < 4; ++reg) {
            float p = 0.f;
#pragma unroll
            for (int c = 0; c < 4; ++c) {
                float v = acc[r][c][reg];
                v = (v > 0.f) ? v : SLOPE * v;
                p = fmaf(v, qv[c], p);
            }
            p += __shfl_xor(p, 1);
            p += __shfl_xor(p, 2);
            p += __shfl_xor(p, 4);
            p += __shfl_xor(p, 8);
            if (lr == 0) atomicAdd(&eo[rowb + reg], p);
        }
    }
}

// ---------------- GCN aggregation (fp16 gather, packed dinv) + bias + relu ----------------

__global__ __launch_bounds__(256) void agg_relu(const u16* __restrict__ h,
                                                const float* __restrict__ dinv,
                                                const int* __restrict__ rowstart,
                                                const int* __restrict__ csr,
                                                const float* __restrict__ bias,
                                                float* __restrict__ out) {
    int wave = threadIdx.x >> 6;
    int lane = threadIdx.x & 63;
    int n = blockIdx.x * 4 + wave;
    if (n >= N_NODES) return;
    int ep = lane >> 5;
    int q  = lane & 31;
    int s = rowstart[n], e1 = rowstart[n + 1];
    float ax = 0.f, ay = 0.f, az = 0.f, aw = 0.f;
    int e = s + ep;
    for (; e + 6 < e1; e += 8) {
        unsigned c0 = (unsigned)csr[e];
        unsigned c1 = (unsigned)csr[e + 2];
        unsigned c2 = (unsigned)csr[e + 4];
        unsigned c3 = (unsigned)csr[e + 6];
        u16 d0 = (u16)(c0 >> 16), d1 = (u16)(c1 >> 16), d2 = (u16)(c2 >> 16), d3 = (u16)(c3 >> 16);
        float dv0 = __half2float(*(const __half*)&d0);
        float dv1 = __half2float(*(const __half*)&d1);
        float dv2 = __half2float(*(const __half*)&d2);
        float dv3 = __half2float(*(const __half*)&d3);
        uint2 w0 = ((const uint2*)(h + (size_t)(c0 & 0xFFFFu) * HID))[q];
        uint2 w1 = ((const uint2*)(h + (size_t)(c1 & 0xFFFFu) * HID))[q];
        uint2 w2 = ((const uint2*)(h + (size_t)(c2 & 0xFFFFu) * HID))[q];
        uint2 w3 = ((const uint2*)(h + (size_t)(c3 & 0xFFFFu) * HID))[q];
        float2 a0 = __half22float2(*(const __half2*)&w0.x), b0 = __half22float2(*(const __half2*)&w0.y);
        float2 a1 = __half22float2(*(const __half2*)&w1.x), b1 = __half22float2(*(const __half2*)&w1.y);
        float2 a2 = __half22float2(*(const __half2*)&w2.x), b2 = __half22float2(*(const __half2*)&w2.y);
        float2 a3 = __half22float2(*(const __half2*)&w3.x), b3 = __half22float2(*(const __half2*)&w3.y);
        ax = fmaf(dv0, a0.x, ax); ay = fmaf(dv0, a0.y, ay); az = fmaf(dv0, b0.x, az); aw = fmaf(dv0, b0.y, aw);
        ax = fmaf(dv1, a1.x, ax); ay = fmaf(dv1, a1.y, ay); az = fmaf(dv1, b1.x, az); aw = fmaf(dv1, b1.y, aw);
        ax = fmaf(dv2, a2.x, ax); ay = fmaf(dv2, a2.y, ay); az = fmaf(dv2, b2.x, az); aw = fmaf(dv2, b2.y, aw);
        ax = fmaf(dv3, a3.x, ax); ay = fmaf(dv3, a3.y, ay); az = fmaf(dv3, b3.x, az); aw = fmaf(dv3, b3.y, aw);
    }
    for (; e < e1; e += 2) {
        unsigned c0 = (unsigned)csr[e];
        u16 d0 = (u16)(c0 >> 16);
        float dv = __half2float(*(const __half*)&d0);
        uint2 w0 = ((const uint2*)(h + (size_t)(c0 & 0xFFFFu) * HID))[q];
        float2 a0 = __half22float2(*(const __half2*)&w0.x);
        float2 b0 = __half22float2(*(const __half2*)&w0.y);
        ax = fmaf(dv, a0.x, ax); ay = fmaf(dv, a0.y, ay);
        az = fmaf(dv, b0.x, az); aw = fmaf(dv, b0.y, aw);
    }
    ax += __shfl_xor(ax, 32);
    ay += __shfl_xor(ay, 32);
    az += __shfl_xor(az, 32);
    aw += __shfl_xor(aw, 32);
    if (ep == 0) {
        float dn = dinv[n];
        float dn2 = dn * dn;
        uint2 hw = ((const uint2*)(h + (size_t)n * HID))[q];
        float2 h0 = __half22float2(*(const __half2*)&hw.x);
        float2 h1 = __half22float2(*(const __half2*)&hw.y);
        float4 bv = ((const float4*)bias)[q];
        float4 o;
        o.x = fmaxf(fmaf(ax, dn, fmaf(h0.x, dn2, bv.x)), 0.f);
        o.y = fmaxf(fmaf(ay, dn, fmaf(h0.y, dn2, bv.y)), 0.f);
        o.z = fmaxf(fmaf(az, dn, fmaf(h1.x, dn2, bv.z)), 0.f);
        o.w = fmaxf(fmaf(aw, dn, fmaf(h1.y, dn2, bv.w)), 0.f);
        ((float4*)(out + (size_t)n * HID))[q] = o;
    }
}

// ---------------- BatchNorm: wide reduce (no fence) + separate tiny finalize ----------

#define BNR_NB 1000

__global__ __launch_bounds__(256) void bn_reduce(const float* __restrict__ x,
                                                 float* __restrict__ acc) {   // stride-16 padded
    __shared__ float s_s[HID], s_sq[HID];
    int tid = threadIdx.x;
    if (tid < HID) { s_s[tid] = 0.f; s_sq[tid] = 0.f; }
    __syncthreads();
    int q  = tid & 31;     // float4 column index
    int rp = tid >> 5;     // 8 row streams
    const int RPB = (N_NODES + BNR_NB - 1) / BNR_NB;   // 50
    int r0 = blockIdx.x * RPB;
    int r1 = min(r0 + RPB, N_NODES);
    float sx = 0.f, sy = 0.f, sz = 0.f, sw = 0.f;
    float qx = 0.f, qy = 0.f, qz = 0.f, qw = 0.f;
    for (int r = r0 + rp; r < r1; r += 8) {
        float4 v = ((const float4*)(x + (size_t)r * HID))[q];
        sx += v.x; sy += v.y; sz += v.z; sw += v.w;
        qx = fmaf(v.x, v.x, qx); qy = fmaf(v.y, v.y, qy);
        qz = fmaf(v.z, v.z, qz); qw = fmaf(v.w, v.w, qw);
    }
    atomicAdd(&s_s[q * 4 + 0], sx);
    atomicAdd(&s_s[q * 4 + 1], sy);
    atomicAdd(&s_s[q * 4 + 2], sz);
    atomicAdd(&s_s[q * 4 + 3], sw);
    atomicAdd(&s_sq[q * 4 + 0], qx);
    atomicAdd(&s_sq[q * 4 + 1], qy);
    atomicAdd(&s_sq[q * 4 + 2], qz);
    atomicAdd(&s_sq[q * 4 + 3], qw);
    __syncthreads();
    if (tid < HID) atomicAdd(&acc[tid * BNACC_STRIDE], s_s[tid]);
    else           atomicAdd(&acc[tid * BNACC_STRIDE], s_sq[tid - HID]);
    // no __threadfence: the kernel boundary provides device-scope visibility
}

__global__ void bn_finalize(const float* __restrict__ acc,
                            const float* __restrict__ gamma, const float* __restrict__ beta,
                            float* __restrict__ bnss) {
    int f = threadIdx.x;   // 0..127
    float st  = acc[f * BNACC_STRIDE];
    float sqt = acc[(HID + f) * BNACC_STRIDE];
    float mean = st * (1.0f / N_NODES);
    float var  = fmaxf(sqt * (1.0f / N_NODES) - mean * mean, 0.f);
    float sc   = gamma[f] * rsqrtf(var + BN_EPS);
    bnss[f] = sc;
    bnss[HID + f] = beta[f] - mean * sc;
}

// ---------------- softmax + pool (gathers emb directly, BN fused) ----------------

__global__ void softmax_pool(const float* __restrict__ e0, const float* __restrict__ e1,
                             const float* __restrict__ e2, const float* __restrict__ bnss3,
                             const int* __restrict__ dpos, const int* __restrict__ dneg,
                             const int* __restrict__ tpos, const int* __restrict__ tneg,
                             const float* __restrict__ e_D, const float* __restrict__ e_T,
                             float* __restrict__ P_D, float* __restrict__ P_T) {
    int j = blockIdx.x;
    int f = threadIdx.x;
    int head = blockIdx.y;
    const int* ia = head ? tpos : dpos;
    const int* ib = head ? tneg : dneg;
    const float* e = head ? e_T : e_D;
    float* P = head ? P_T : P_D;
    int node = (j < BATCH) ? ia[j] : ib[j - BATCH];
    float l0 = e[j], l1 = e[2 * BATCH + j], l2 = e[4 * BATCH + j];
    float m = fmaxf(l0, fmaxf(l1, l2));
    float a0 = expf(l0 - m), a1 = expf(l1 - m), a2 = expf(l2 - m);
    float inv = 1.0f / (a0 + a1 + a2);
    float v0 = fmaf(e0[(size_t)node * HID + f], bnss3[f],           bnss3[HID + f]);
    float v1 = fmaf(e1[(size_t)node * HID + f], bnss3[2 * HID + f], bnss3[3 * HID + f]);
    float v2 = fmaf(e2[(size_t)node * HID + f], bnss3[4 * HID + f], bnss3[5 * HID + f]);
    P[(size_t)j * HID + f] = (a0 * v0 + a1 * v1 + a2 * v2) * inv;
}

// ---------------- output head: 4 segments batched via blockIdx.y ----------------

__global__ __launch_bounds__(256) void head_gemm(const float* __restrict__ P_D,
                                                 const float* __restrict__ P_T,
                                                 const float* __restrict__ B,
                                                 const float* __restrict__ bias,
                                                 float* __restrict__ out) {
    constexpr int BM = 64, BK = 32, BN = OUT_DIM, TM = 4, TN = 4;
    __shared__ float As[BK][BM];
    __shared__ float Bs[BK][BN];
    const int y = blockIdx.y;
    const float* A = ((y & 1) ? P_T : P_D) + (size_t)(y >> 1) * BATCH * HID;
    float* C = out + (size_t)y * BATCH * OUT_DIM;
    const int tid = threadIdx.x;
    const int tx = tid & 15, ty = tid >> 4;
    const int rowBase = blockIdx.x * BM;
    float acc[TM][TN];
#pragma unroll
    for (int i = 0; i < TM; ++i)
#pragma unroll
        for (int j = 0; j < TN; ++j) acc[i][j] = 0.f;

    for (int kk = 0; kk < HID; kk += BK) {
#pragma unroll
        for (int i = tid; i < (BM * BK) / 4; i += 256) {
            int m  = i >> 3;
            int kq = i & 7;
            float4 v = *(const float4*)(A + (size_t)(rowBase + m) * HID + kk + kq * 4);
            As[kq * 4 + 0][m] = v.x;
            As[kq * 4 + 1][m] = v.y;
            As[kq * 4 + 2][m] = v.z;
            As[kq * 4 + 3][m] = v.w;
        }
#pragma unroll
        for (int i = tid; i < (BK * BN) / 4; i += 256) {
            int k  = i / (BN / 4);
            int n4 = i % (BN / 4);
            *(float4*)&Bs[k][n4 * 4] = *(const float4*)(B + (size_t)(kk + k) * BN + n4 * 4);
        }
        __syncthreads();
#pragma unroll 8
        for (int k = 0; k < BK; ++k) {
            float a[TM], b[TN];
#pragma unroll
            for (int i = 0; i < TM; ++i) a[i] = As[k][ty * TM + i];
#pragma unroll
            for (int j = 0; j < TN; ++j) b[j] = Bs[k][tx * TN + j];
#pragma unroll
            for (int i = 0; i < TM; ++i)
#pragma unroll
                for (int j = 0; j < TN; ++j)
                    acc[i][j] = fmaf(a[i], b[j], acc[i][j]);
        }
        __syncthreads();
    }
#pragma unroll
    for (int i = 0; i < TM; ++i) {
        int grow = rowBase + ty * TM + i;
#pragma unroll
        for (int j = 0; j < TN; ++j)
            C[(size_t)grow * BN + tx * TN + j] = acc[i][j] + bias[tx * TN + j];
    }
}

// ---------------- host ----------------

extern "C" void kernel_launch(void* const* d_in, const int* in_sizes, int n_in,
                              void* d_out, int out_size, void* d_ws, size_t ws_size,
                              hipStream_t stream) {
    const float* x          = (const float*)d_in[0];
    const int*   ei         = (const int*)d_in[1];
    const int*   srcp       = ei;
    const int*   dstp       = ei + N_EDGES;
    const int*   drug_pos   = (const int*)d_in[2];
    const int*   target_pos = (const int*)d_in[3];
    const int*   drug_neg   = (const int*)d_in[4];
    const int*   target_neg = (const int*)d_in[5];
    const float* gcn_w[3]   = {(const float*)d_in[7], (const float*)d_in[9], (const float*)d_in[11]};
    const float* gcn_b[3]   = {(const float*)d_in[8], (const float*)d_in[10], (const float*)d_in[12]};
    const float* gamma      = (const float*)d_in[13];
    const float* beta       = (const float*)d_in[14];
    const float* W_D        = (const float*)d_in[15];
    const float* W_T        = (const float*)d_in[16];
    const float* q_D        = (const float*)d_in[17];
    const float* q_T        = (const float*)d_in[18];
    const float* out_w      = (const float*)d_in[19];
    const float* out_b      = (const float*)d_in[20];
    float*       out        = (float*)d_out;

    // ---- workspace (~110 MB) with phase overlays ----
    char* p = (char*)d_ws;
    auto alloc = [&](size_t bytes) -> char* {
        char* r = p;
        p += (bytes + 255) & ~(size_t)255;
        return r;
    };
    char*  reg1  = alloc(sizeof(float) * (size_t)N_NODES * HID);   // h (fp16) | P_D+P_T
    float* emb0  = (float*)alloc(sizeof(float) * (size_t)N_NODES * HID);
    float* emb1  = (float*)alloc(sizeof(float) * (size_t)N_NODES * HID);
    float* emb2  = (float*)alloc(sizeof(float) * (size_t)N_NODES * HID);
    float* ebuf  = (float*)alloc(sizeof(float) * (size_t)2 * 3 * 2 * BATCH);
    u16*   w0swz = (u16*)alloc(sizeof(u16) * 2 * HID * IN_DIM);
    u16*   w1swz = (u16*)alloc(sizeof(u16) * 2 * HID * HID);
    u16*   w2swz = (u16*)alloc(sizeof(u16) * 2 * HID * HID);
    u16*   wDTswz = (u16*)alloc(sizeof(u16) * 4 * HID * HID);
    float* wt    = (float*)alloc(sizeof(float) * OUT_DIM * HID);
    int*   rowstart = (int*)alloc(sizeof(int) * (N_NODES + 1));
    int*   csr   = (int*)alloc(sizeof(int) * N_EDGES);
    unsigned* pairs = (unsigned*)alloc(sizeof(unsigned) * N_EDGES);
    float* dinvp = (float*)alloc(sizeof(float) * N_NODES);
    int*   bucketCnt  = (int*)alloc(sizeof(int) * 256);
    int*   bucketBase = (int*)alloc(sizeof(int) * (NBKT + 1));
    int*   gcursor    = (int*)alloc(sizeof(int) * 256);
    float* bnacc3 = (float*)alloc(sizeof(float) * 3 * BNACC_PER_LAYER);
    float* bnss3  = (float*)alloc(sizeof(float) * 3 * 2 * HID);
    if ((size_t)(p - (char*)d_ws) > ws_size) return;   // visible failure if ws too small

    u16*   hbuf = (u16*)reg1;
    float* P_D  = (float*)reg1;                         // pools phase: h is dead
    float* P_T  = P_D + (size_t)2 * BATCH * HID;
    float* e_D  = ebuf;
    float* e_T  = ebuf + 3 * 2 * BATCH;
    float* embp[3] = {emb0, emb1, emb2};
    const u16* wswz[3] = {w0swz, w1swz, w2swz};

    // ---- prep ----
    prep<<<(PTOT + 255) / 256, 256, 0, stream>>>(
        gcn_w[0], gcn_w[1], gcn_w[2], W_D, W_T, out_w,
        w0swz, w1swz, w2swz, wDTswz, wt, bnacc3, bucketCnt, ebuf);

    // ---- bucketed CSR build ----
    bucket_count<<<NB_A, 256, 0, stream>>>(dstp, bucketCnt);
    bucket_scan<<<1, 256, 0, stream>>>(bucketCnt, bucketBase, gcursor, rowstart);
    bucket_scatter<<<NB_A, 256, 0, stream>>>(srcp, dstp, gcursor, pairs);
    bucket_build<<<NBKT, 256, 0, stream>>>(pairs, bucketBase, rowstart, dinvp, csr);
    csr_pack<<<(N_EDGES + 255) / 256, 256, 0, stream>>>(csr, dinvp);

    // ---- 3 GCN layers (BN fused into next consumer) ----
    const int GB = ((N_NODES + 127) / 128) * 2;   // 782 blocks
    for (int l = 0; l < 3; ++l) {
        int din = (l == 0) ? IN_DIM : HID;
        const float* Ain = (l == 0) ? x : embp[l - 1];
        const float* bnss = (l == 0) ? nullptr : (bnss3 + (l - 1) * 2 * HID);
        gemm_tile<<<GB, 256, 0, stream>>>(Ain, bnss, wswz[l], hbuf, N_NODES, din);
        agg_relu<<<(N_NODES + 3) / 4, 256, 0, stream>>>(hbuf, dinvp, rowstart, csr, gcn_b[l], embp[l]);
        bn_reduce<<<BNR_NB, 256, 0, stream>>>(embp[l], bnacc3 + l * BNACC_PER_LAYER);
        bn_finalize<<<1, HID, 0, stream>>>(bnacc3 + l * BNACC_PER_LAYER, gamma, beta,
                                           bnss3 + l * 2 * HID);
    }

    // ---- attention pooling (H never materialized; e accumulated in pool_gemm) ----
    const int RG = 3 * 2 * BATCH;
    pool_gemm<<<dim3((RG / 128) * 2, 2), 256, 0, stream>>>(
        emb0, emb1, emb2, bnss3, drug_pos, drug_neg, target_pos, target_neg,
        wDTswz, q_D, q_T, e_D, e_T);
    softmax_pool<<<dim3(2 * BATCH, 2), HID, 0, stream>>>(
        emb0, emb1, emb2, bnss3, drug_pos, drug_neg, target_pos, target_neg,
        e_D, e_T, P_D, P_T);

    // ---- output head ----
    head_gemm<<<dim3(BATCH / 64, 4), 256, 0, stream>>>(P_D, P_T, wt, out_b, out);
}